// Round 1
// baseline (247.978 us; speedup 1.0000x reference)
//
#include <hip/hip_runtime.h>
#include <hip/hip_bf16.h>
#include <math.h>

typedef short bf16x8 __attribute__((ext_vector_type(8)));
typedef float f32x4 __attribute__((ext_vector_type(4)));
typedef unsigned int u32;

#define B_DIM 8192
#define H_DIM 1024
#define NPATH 256
#define NSTEP 50

__device__ __forceinline__ void gld_lds16(const void* g, void* lds) {
  __builtin_amdgcn_global_load_lds(
      (const __attribute__((address_space(1))) u32*)g,
      (__attribute__((address_space(3))) u32*)lds, 16, 0, 0);
}

// ---------- fp32 -> bf16 cast (vectorized float4 in, 4x bf16 out) ----------
__global__ __launch_bounds__(256) void cast_f32_bf16(const float* __restrict__ in,
                                                     __hip_bfloat16* __restrict__ out,
                                                     int n4) {
  int i = blockIdx.x * 256 + threadIdx.x;
  if (i < n4) {
    float4 v = ((const float4*)in)[i];
    union { __hip_bfloat16 h[4]; short4 s; } u;
    u.h[0] = __float2bfloat16(v.x);
    u.h[1] = __float2bfloat16(v.y);
    u.h[2] = __float2bfloat16(v.z);
    u.h[3] = __float2bfloat16(v.w);
    ((short4*)out)[i] = u.s;
  }
}

// ---------- transpose + cast: W[R][C] fp32 -> Wt[C][R] bf16 ----------
__global__ void transpose_cast(const float* __restrict__ W,
                               __hip_bfloat16* __restrict__ Wt,
                               int R, int C) {
  __shared__ float t[32][33];
  int tx = threadIdx.x, ty = threadIdx.y;
  int c = blockIdx.x * 32 + tx;
  int r = blockIdx.y * 32 + ty;
  t[ty][tx] = W[(size_t)r * C + c];
  __syncthreads();
  int co = blockIdx.x * 32 + ty;   // output row (old col)
  int ro = blockIdx.y * 32 + tx;   // output col (old row)
  Wt[(size_t)co * R + ro] = __float2bfloat16(t[tx][ty]);
}

// ---------- noise sum over last axis: [B*P][50] -> [B*P] ----------
__global__ __launch_bounds__(256) void noise_sum_kernel(const float* __restrict__ noise,
                                                        float* __restrict__ ns) {
  int row = blockIdx.x * 256 + threadIdx.x;   // 0 .. B*P-1
  const float2* p = (const float2*)(noise + (size_t)row * NSTEP);
  float s = 0.f;
#pragma unroll
  for (int i = 0; i < NSTEP / 2; ++i) {
    float2 v = p[i];
    s += v.x + v.y;
  }
  ns[row] = s;
}

// ---------- feedback: f[b] = sigmoid(dot(h2b[b,:], W_fb) + b_fb) ----------
__global__ __launch_bounds__(256) void feedback_kernel(const __hip_bfloat16* __restrict__ h2b,
                                                       const float* __restrict__ Wfb,
                                                       const float* __restrict__ bfb,
                                                       float* __restrict__ f) {
  int wid = threadIdx.x >> 6;
  int lane = threadIdx.x & 63;
  int row = blockIdx.x * 4 + wid;
  const __hip_bfloat16* hrow = h2b + (size_t)row * H_DIM;
  float s = 0.f;
#pragma unroll
  for (int i = lane; i < H_DIM; i += 64) {
    s += __bfloat162float(hrow[i]) * Wfb[i];
  }
#pragma unroll
  for (int off = 32; off > 0; off >>= 1) s += __shfl_down(s, off);
  if (lane == 0) {
    float z = s + bfb[0];
    f[row] = 1.0f / (1.0f + expf(-z));
  }
}

// ---------- endpoints: eb[b][p] = bf16(f[b]*DI + SQDT*ns[b][p]) ----------
__global__ __launch_bounds__(256) void endpoints_kernel(const float* __restrict__ ns,
                                                        const float* __restrict__ f,
                                                        __hip_bfloat16* __restrict__ eb,
                                                        float DI, float SQDT) {
  int i = blockIdx.x * 256 + threadIdx.x;  // 0 .. B*P-1
  int b = i >> 8;
  eb[i] = __float2bfloat16(f[b] * DI + SQDT * ns[i]);
}

// ---------- bf16 MFMA GEMM: A[M][K] x Bt[N][K]^T + bias ----------
// MODE 0: relu -> bf16 out
// MODE 2: + extra(bf16) -> bf16 out
// MODE 3: fp32 out
template <int MODE>
__global__ __launch_bounds__(256) void gemm_bt(const __hip_bfloat16* __restrict__ A,
                                               const __hip_bfloat16* __restrict__ Bt,
                                               const float* __restrict__ bias,
                                               const __hip_bfloat16* __restrict__ extra,
                                               void* __restrict__ out,
                                               int M, int N, int K) {
  __shared__ __hip_bfloat16 As[128 * 64];
  __shared__ __hip_bfloat16 Bs[128 * 64];

  const int tid = threadIdx.x;
  const int lane = tid & 63;
  const int wid = tid >> 6;
  const int wr = wid >> 1, wc = wid & 1;
  const int bn = blockIdx.x, bm = blockIdx.y;

  const int frow = lane & 15;  // fragment row/col within 16
  const int kgrp = lane >> 4;  // 0..3, k-subgroup

  f32x4 acc[4][4];
#pragma unroll
  for (int m = 0; m < 4; ++m)
#pragma unroll
    for (int n = 0; n < 4; ++n) acc[m][n] = (f32x4){0.f, 0.f, 0.f, 0.f};

  for (int kt = 0; kt < K; kt += 64) {
    // stage A tile (128x64 bf16 = 16KB) and Bt tile via global_load_lds w16
#pragma unroll
    for (int r = 0; r < 4; ++r) {
      int c = r * 256 + tid;     // 16B chunk index, 0..1023
      int row = c >> 3;          // 8 chunks per 64-elem row
      int cc = c & 7;
      const char* ga = (const char*)A + ((size_t)(bm * 128 + row) * K + kt) * 2 + cc * 16;
      gld_lds16(ga, (char*)As + c * 16);
      const char* gb = (const char*)Bt + ((size_t)(bn * 128 + row) * K + kt) * 2 + cc * 16;
      gld_lds16(gb, (char*)Bs + c * 16);
    }
    __syncthreads();  // drains vmcnt before barrier

#pragma unroll
    for (int kk = 0; kk < 64; kk += 32) {
      bf16x8 af[4], bfr[4];
#pragma unroll
      for (int m = 0; m < 4; ++m)
        af[m] = *(const bf16x8*)(As + (wr * 64 + m * 16 + frow) * 64 + kk + kgrp * 8);
#pragma unroll
      for (int n = 0; n < 4; ++n)
        bfr[n] = *(const bf16x8*)(Bs + (wc * 64 + n * 16 + frow) * 64 + kk + kgrp * 8);
#pragma unroll
      for (int m = 0; m < 4; ++m)
#pragma unroll
        for (int n = 0; n < 4; ++n)
          acc[m][n] = __builtin_amdgcn_mfma_f32_16x16x32_bf16(af[m], bfr[n], acc[m][n], 0, 0, 0);
    }
    __syncthreads();
  }

  // epilogue: C/D layout col = lane&15, row = (lane>>4)*4 + j  [verified mapping]
  const int r0 = bm * 128 + wr * 64;
  const int c0 = bn * 128 + wc * 64;
#pragma unroll
  for (int n = 0; n < 4; ++n) {
    int col = c0 + n * 16 + frow;
    float bv = bias[col];
#pragma unroll
    for (int m = 0; m < 4; ++m) {
#pragma unroll
      for (int j = 0; j < 4; ++j) {
        int row = r0 + m * 16 + kgrp * 4 + j;
        float v = acc[m][n][j] + bv;
        if (MODE == 0) {
          v = fmaxf(v, 0.f);
          ((__hip_bfloat16*)out)[(size_t)row * N + col] = __float2bfloat16(v);
        } else if (MODE == 2) {
          v += __bfloat162float(extra[(size_t)row * N + col]);
          ((__hip_bfloat16*)out)[(size_t)row * N + col] = __float2bfloat16(v);
        } else {
          ((float*)out)[(size_t)row * N + col] = v;
        }
      }
    }
  }
}

extern "C" void kernel_launch(void* const* d_in, const int* in_sizes, int n_in,
                              void* d_out, int out_size, void* d_ws, size_t ws_size,
                              hipStream_t stream) {
  (void)in_sizes; (void)n_in; (void)out_size;
  const float* x     = (const float*)d_in[0];
  const float* W_in  = (const float*)d_in[1];
  const float* b_in  = (const float*)d_in[2];
  const float* W_hid = (const float*)d_in[3];
  const float* b_hid = (const float*)d_in[4];
  const float* W_fb  = (const float*)d_in[5];
  const float* b_fb  = (const float*)d_in[6];
  const float* W_agg = (const float*)d_in[7];
  const float* b_agg = (const float*)d_in[8];
  const float* W_out = (const float*)d_in[9];
  const float* b_out = (const float*)d_in[10];
  const float* noise = (const float*)d_in[11];

  const int B = B_DIM, H = H_DIM, P = NPATH;

  size_t off = 0;
  char* base = (char*)d_ws;
  auto take = [&](size_t bytes) -> char* {
    char* r = base + off;
    off = (off + bytes + 255) & ~(size_t)255;
    return r;
  };
  __hip_bfloat16* xb    = (__hip_bfloat16*)take((size_t)B * H * 2);  // also reused for `combined`
  __hip_bfloat16* h1b   = (__hip_bfloat16*)take((size_t)B * H * 2);
  __hip_bfloat16* h2b   = (__hip_bfloat16*)take((size_t)B * H * 2);
  __hip_bfloat16* wtin  = (__hip_bfloat16*)take((size_t)H * H * 2);
  __hip_bfloat16* wthid = (__hip_bfloat16*)take((size_t)H * H * 2);
  __hip_bfloat16* wtagg = (__hip_bfloat16*)take((size_t)H * P * 2);
  __hip_bfloat16* wtout = (__hip_bfloat16*)take((size_t)H * H * 2);

  float* ns; float* fbv; __hip_bfloat16* eb;
  size_t scratch_bytes = (size_t)B * P * 4 + 4096 + (size_t)B * 4 + (size_t)B * P * 2;
  if (ws_size >= off + scratch_bytes) {
    ns  = (float*)take((size_t)B * P * 4);
    fbv = (float*)take((size_t)B * 4);
    eb  = (__hip_bfloat16*)take((size_t)B * P * 2);
  } else {
    // d_out (32MB fp32) is dead until the final GEMM; use it as scratch
    char* q = (char*)d_out;
    ns  = (float*)q;
    fbv = (float*)(q + (size_t)B * P * 4);
    eb  = (__hip_bfloat16*)(q + (size_t)B * P * 4 + ((B * 4 + 255) & ~255));
  }

  // host-side constants (deterministic, matches jnp fp32 evaluation)
  float dt = 1.0f / NSTEP;
  float DI = 0.f;
  for (int j = 0; j < NSTEP; ++j) DI += expf(-0.1f * ((float)j * dt));
  DI *= dt;
  float SQDT = sqrtf(dt);

  dim3 tb(32, 32);
  cast_f32_bf16<<<(B * H / 4 + 255) / 256, 256, 0, stream>>>(x, xb, B * H / 4);
  transpose_cast<<<dim3(H / 32, H / 32), tb, 0, stream>>>(W_in, wtin, H, H);
  transpose_cast<<<dim3(H / 32, H / 32), tb, 0, stream>>>(W_hid, wthid, H, H);
  transpose_cast<<<dim3(H / 32, P / 32), tb, 0, stream>>>(W_agg, wtagg, P, H);
  transpose_cast<<<dim3(H / 32, H / 32), tb, 0, stream>>>(W_out, wtout, H, H);
  noise_sum_kernel<<<B * P / 256, 256, 0, stream>>>(noise, ns);

  dim3 gg(H / 128, B / 128);
  gemm_bt<0><<<gg, 256, 0, stream>>>(xb, wtin, b_in, nullptr, h1b, B, H, H);
  gemm_bt<0><<<gg, 256, 0, stream>>>(h1b, wthid, b_hid, nullptr, h2b, B, H, H);
  feedback_kernel<<<B / 4, 256, 0, stream>>>(h2b, W_fb, b_fb, fbv);
  endpoints_kernel<<<B * P / 256, 256, 0, stream>>>(ns, fbv, eb, DI, SQDT);
  gemm_bt<2><<<gg, 256, 0, stream>>>(eb, wtagg, b_agg, h2b, xb, B, H, P);
  gemm_bt<3><<<gg, 256, 0, stream>>>(xb, wtout, b_out, nullptr, d_out, B, H, H);
}

// Round 2
// 219.937 us; speedup vs baseline: 1.1275x; 1.1275x over previous
//
#include <hip/hip_runtime.h>
#include <hip/hip_bf16.h>
#include <math.h>

typedef short bf16x8 __attribute__((ext_vector_type(8)));
typedef float f32x4 __attribute__((ext_vector_type(4)));
typedef unsigned int u32;

#define B_DIM 8192
#define H_DIM 1024
#define NPATH 256
#define NSTEP 50

__device__ __forceinline__ void gld_lds16(const void* g, void* lds) {
  __builtin_amdgcn_global_load_lds(
      (const __attribute__((address_space(1))) u32*)g,
      (__attribute__((address_space(3))) u32*)lds, 16, 0, 0);
}

// ---------- fp32 -> bf16 cast (vectorized float4 in, 4x bf16 out) ----------
__global__ __launch_bounds__(256) void cast_f32_bf16(const float* __restrict__ in,
                                                     __hip_bfloat16* __restrict__ out,
                                                     int n4) {
  int i = blockIdx.x * 256 + threadIdx.x;
  if (i < n4) {
    float4 v = ((const float4*)in)[i];
    union { __hip_bfloat16 h[4]; short4 s; } u;
    u.h[0] = __float2bfloat16(v.x);
    u.h[1] = __float2bfloat16(v.y);
    u.h[2] = __float2bfloat16(v.z);
    u.h[3] = __float2bfloat16(v.w);
    ((short4*)out)[i] = u.s;
  }
}

// ---------- transpose + cast: W[R][C] fp32 -> Wt[C][R] bf16 ----------
__global__ void transpose_cast(const float* __restrict__ W,
                               __hip_bfloat16* __restrict__ Wt,
                               int R, int C) {
  __shared__ float t[32][33];
  int tx = threadIdx.x, ty = threadIdx.y;
  int c = blockIdx.x * 32 + tx;
  int r = blockIdx.y * 32 + ty;
  t[ty][tx] = W[(size_t)r * C + c];
  __syncthreads();
  int co = blockIdx.x * 32 + ty;   // output row (old col)
  int ro = blockIdx.y * 32 + tx;   // output col (old row)
  Wt[(size_t)co * R + ro] = __float2bfloat16(t[tx][ty]);
}

// ---------- feedback: f[b] = sigmoid(dot(h2b[b,:], W_fb) + b_fb) ----------
__global__ __launch_bounds__(256) void feedback_kernel(const __hip_bfloat16* __restrict__ h2b,
                                                       const float* __restrict__ Wfb,
                                                       const float* __restrict__ bfb,
                                                       float* __restrict__ f) {
  int wid = threadIdx.x >> 6;
  int lane = threadIdx.x & 63;
  int row = blockIdx.x * 4 + wid;
  const __hip_bfloat16* hrow = h2b + (size_t)row * H_DIM;
  float s = 0.f;
#pragma unroll
  for (int i = lane; i < H_DIM; i += 64) {
    s += __bfloat162float(hrow[i]) * Wfb[i];
  }
#pragma unroll
  for (int off = 32; off > 0; off >>= 1) s += __shfl_down(s, off);
  if (lane == 0) {
    float z = s + bfb[0];
    f[row] = 1.0f / (1.0f + expf(-z));
  }
}

// ---------- endpoints: eb[b][p] = bf16(f[b]*DI + SQDT*ns[b][p]) ----------
__global__ __launch_bounds__(256) void endpoints_kernel(const float* __restrict__ ns,
                                                        const float* __restrict__ f,
                                                        __hip_bfloat16* __restrict__ eb,
                                                        float DI, float SQDT) {
  int i = blockIdx.x * 256 + threadIdx.x;  // 0 .. B*P-1
  int b = i >> 8;
  eb[i] = __float2bfloat16(f[b] * DI + SQDT * ns[i]);
}

// ---------- bf16 MFMA GEMM: A[M][K] x Bt[N][K]^T + bias ----------
// MODE 0: relu -> bf16 out
// MODE 2: + extra(bf16) -> bf16 out
// MODE 3: fp32 out
// WITH_NOISE: even blockIdx.x blocks instead reduce `noise` rows into `ns`
// (heterogeneous co-scheduling: BW-bound noise waves overlap MFMA-bound GEMM
//  waves on the same CUs; GEMM alone leaves ~5 TB/s HBM headroom).
template <int MODE, bool WITH_NOISE>
__global__ __launch_bounds__(256) void gemm_bt(const __hip_bfloat16* __restrict__ A,
                                               const __hip_bfloat16* __restrict__ Bt,
                                               const float* __restrict__ bias,
                                               const __hip_bfloat16* __restrict__ extra,
                                               void* __restrict__ out,
                                               int M, int N, int K, int gx,
                                               const float* __restrict__ noise,
                                               float* __restrict__ ns,
                                               int noiseRowStart, int noiseRowCount) {
  int gb;
  if (WITH_NOISE) {
    int bid = blockIdx.x;
    if ((bid & 1) == 0) {
      // ---- noise-reduction block ----
      int j = bid >> 1;
      int nblocks = gridDim.x >> 1;
      for (int r = j * 256 + threadIdx.x; r < noiseRowCount; r += nblocks * 256) {
        int row = noiseRowStart + r;
        const float2* p = (const float2*)(noise + (size_t)row * NSTEP);
        float s = 0.f;
#pragma unroll
        for (int i = 0; i < NSTEP / 2; ++i) {
          float2 v = p[i];
          s += v.x + v.y;
        }
        ns[row] = s;
      }
      return;
    }
    gb = bid >> 1;
  } else {
    gb = blockIdx.x;
  }

  __shared__ __hip_bfloat16 As[128 * 64];
  __shared__ __hip_bfloat16 Bs[128 * 64];

  const int tid = threadIdx.x;
  const int lane = tid & 63;
  const int wid = tid >> 6;
  const int wr = wid >> 1, wc = wid & 1;
  const int bn = gb % gx, bm = gb / gx;

  const int frow = lane & 15;  // fragment row/col within 16
  const int kgrp = lane >> 4;  // 0..3, k-subgroup

  f32x4 acc[4][4];
#pragma unroll
  for (int m = 0; m < 4; ++m)
#pragma unroll
    for (int n = 0; n < 4; ++n) acc[m][n] = (f32x4){0.f, 0.f, 0.f, 0.f};

  for (int kt = 0; kt < K; kt += 64) {
    // stage A tile (128x64 bf16 = 16KB) and Bt tile via global_load_lds w16
#pragma unroll
    for (int r = 0; r < 4; ++r) {
      int c = r * 256 + tid;     // 16B chunk index, 0..1023
      int row = c >> 3;          // 8 chunks per 64-elem row
      int cc = c & 7;
      const char* ga = (const char*)A + ((size_t)(bm * 128 + row) * K + kt) * 2 + cc * 16;
      gld_lds16(ga, (char*)As + c * 16);
      const char* gb_ = (const char*)Bt + ((size_t)(bn * 128 + row) * K + kt) * 2 + cc * 16;
      gld_lds16(gb_, (char*)Bs + c * 16);
    }
    __syncthreads();  // drains vmcnt before barrier

#pragma unroll
    for (int kk = 0; kk < 64; kk += 32) {
      bf16x8 af[4], bfr[4];
#pragma unroll
      for (int m = 0; m < 4; ++m)
        af[m] = *(const bf16x8*)(As + (wr * 64 + m * 16 + frow) * 64 + kk + kgrp * 8);
#pragma unroll
      for (int n = 0; n < 4; ++n)
        bfr[n] = *(const bf16x8*)(Bs + (wc * 64 + n * 16 + frow) * 64 + kk + kgrp * 8);
#pragma unroll
      for (int m = 0; m < 4; ++m)
#pragma unroll
        for (int n = 0; n < 4; ++n)
          acc[m][n] = __builtin_amdgcn_mfma_f32_16x16x32_bf16(af[m], bfr[n], acc[m][n], 0, 0, 0);
    }
    __syncthreads();
  }

  // epilogue: C/D layout col = lane&15, row = (lane>>4)*4 + j  [verified mapping]
  const int r0 = bm * 128 + wr * 64;
  const int c0 = bn * 128 + wc * 64;
#pragma unroll
  for (int n = 0; n < 4; ++n) {
    int col = c0 + n * 16 + frow;
    float bv = bias[col];
#pragma unroll
    for (int m = 0; m < 4; ++m) {
#pragma unroll
      for (int j = 0; j < 4; ++j) {
        int row = r0 + m * 16 + kgrp * 4 + j;
        float v = acc[m][n][j] + bv;
        if (MODE == 0) {
          v = fmaxf(v, 0.f);
          ((__hip_bfloat16*)out)[(size_t)row * N + col] = __float2bfloat16(v);
        } else if (MODE == 2) {
          v += __bfloat162float(extra[(size_t)row * N + col]);
          ((__hip_bfloat16*)out)[(size_t)row * N + col] = __float2bfloat16(v);
        } else {
          ((float*)out)[(size_t)row * N + col] = v;
        }
      }
    }
  }
}

extern "C" void kernel_launch(void* const* d_in, const int* in_sizes, int n_in,
                              void* d_out, int out_size, void* d_ws, size_t ws_size,
                              hipStream_t stream) {
  (void)in_sizes; (void)n_in; (void)out_size;
  const float* x     = (const float*)d_in[0];
  const float* W_in  = (const float*)d_in[1];
  const float* b_in  = (const float*)d_in[2];
  const float* W_hid = (const float*)d_in[3];
  const float* b_hid = (const float*)d_in[4];
  const float* W_fb  = (const float*)d_in[5];
  const float* b_fb  = (const float*)d_in[6];
  const float* W_agg = (const float*)d_in[7];
  const float* b_agg = (const float*)d_in[8];
  const float* W_out = (const float*)d_in[9];
  const float* b_out = (const float*)d_in[10];
  const float* noise = (const float*)d_in[11];

  const int B = B_DIM, H = H_DIM, P = NPATH;
  const int R = B * P;

  size_t off = 0;
  char* base = (char*)d_ws;
  auto take = [&](size_t bytes) -> char* {
    char* r = base + off;
    off = (off + bytes + 255) & ~(size_t)255;
    return r;
  };
  __hip_bfloat16* xb    = (__hip_bfloat16*)take((size_t)B * H * 2);  // also reused for `combined`
  __hip_bfloat16* h1b   = (__hip_bfloat16*)take((size_t)B * H * 2);
  __hip_bfloat16* h2b   = (__hip_bfloat16*)take((size_t)B * H * 2);
  __hip_bfloat16* wtin  = (__hip_bfloat16*)take((size_t)H * H * 2);
  __hip_bfloat16* wthid = (__hip_bfloat16*)take((size_t)H * H * 2);
  __hip_bfloat16* wtagg = (__hip_bfloat16*)take((size_t)H * P * 2);
  __hip_bfloat16* wtout = (__hip_bfloat16*)take((size_t)H * H * 2);

  float* ns; float* fbv; __hip_bfloat16* eb;
  size_t scratch_bytes = (size_t)R * 4 + 4096 + (size_t)B * 4 + (size_t)R * 2;
  if (ws_size >= off + scratch_bytes) {
    ns  = (float*)take((size_t)R * 4);
    fbv = (float*)take((size_t)B * 4);
    eb  = (__hip_bfloat16*)take((size_t)R * 2);
  } else {
    // d_out (32MB fp32) is dead until the final GEMM; use it as scratch
    char* q = (char*)d_out;
    ns  = (float*)q;
    fbv = (float*)(q + (size_t)R * 4);
    eb  = (__hip_bfloat16*)(q + (size_t)R * 4 + ((B * 4 + 255) & ~255));
  }

  // host-side constants (deterministic, matches jnp fp32 evaluation)
  float dt = 1.0f / NSTEP;
  float DI = 0.f;
  for (int j = 0; j < NSTEP; ++j) DI += expf(-0.1f * ((float)j * dt));
  DI *= dt;
  float SQDT = sqrtf(dt);

  dim3 tb(32, 32);
  cast_f32_bf16<<<(B * H / 4 + 255) / 256, 256, 0, stream>>>(x, xb, B * H / 4);
  transpose_cast<<<dim3(H / 32, H / 32), tb, 0, stream>>>(W_in, wtin, H, H);
  transpose_cast<<<dim3(H / 32, H / 32), tb, 0, stream>>>(W_hid, wthid, H, H);
  transpose_cast<<<dim3(H / 32, P / 32), tb, 0, stream>>>(W_agg, wtagg, P, H);
  transpose_cast<<<dim3(H / 32, H / 32), tb, 0, stream>>>(W_out, wtout, H, H);

  const int gx = H / 128;                 // 8
  const int nGemm = gx * (B / 128);       // 512

  // trunk GEMMs with co-scheduled noise reduction (half the rows each)
  gemm_bt<0, true><<<2 * nGemm, 256, 0, stream>>>(xb, wtin, b_in, nullptr, h1b,
                                                  B, H, H, gx, noise, ns, 0, R / 2);
  gemm_bt<0, true><<<2 * nGemm, 256, 0, stream>>>(h1b, wthid, b_hid, nullptr, h2b,
                                                  B, H, H, gx, noise, ns, R / 2, R - R / 2);
  feedback_kernel<<<B / 4, 256, 0, stream>>>(h2b, W_fb, b_fb, fbv);
  endpoints_kernel<<<R / 256, 256, 0, stream>>>(ns, fbv, eb, DI, SQDT);
  gemm_bt<2, false><<<nGemm, 256, 0, stream>>>(eb, wtagg, b_agg, h2b, xb,
                                               B, H, P, gx, nullptr, nullptr, 0, 0);
  gemm_bt<3, false><<<nGemm, 256, 0, stream>>>(xb, wtout, b_out, nullptr, d_out,
                                               B, H, H, gx, nullptr, nullptr, 0, 0);
}